// Round 1
// baseline (184.711 us; speedup 1.0000x reference)
//
#include <hip/hip_runtime.h>

#define NU 60082
#define NST 14695
#define D 128
#define B 8
#define K 32

// ws layout (floats):
//   [0..127]   v      = proj_w @ w_st
//   [128]      c      = proj_b . w_st
//   [136..143] uc[b]  = user_out[b] + b_st  (per-batch additive constant)
//   [144..399] now_val[b*K+k] = alpha[n] * (station_embedding[n] . w_st)
//   [400..655] his_val[b*K+k] = alpha[n] * (MLP(rfe[n]) . w_st)
#define WS_V   0
#define WS_C   128
#define WS_UC  136
#define WS_NOW 144
#define WS_HIS 400

__global__ __launch_bounds__(256) void k_prep(
    const float* __restrict__ user_embedding,
    const float* __restrict__ station_embedding,
    const float* __restrict__ raw_field_embed,
    const int* __restrict__ his_nodes,
    const int* __restrict__ now_nodes,
    const int* __restrict__ user_id,
    const float* __restrict__ user_emb_table,
    const float* __restrict__ proj_w,
    const float* __restrict__ proj_b,
    const float* __restrict__ theta,
    const float* __restrict__ alpha,
    const float* __restrict__ w_his1,
    const float* __restrict__ b_his1,
    const float* __restrict__ w_his2,
    const float* __restrict__ b_his2,
    const float* __restrict__ w_st,
    const float* __restrict__ b_st,
    const float* __restrict__ w_u,
    const float* __restrict__ b_u,
    float* __restrict__ ws)
{
    const int t = threadIdx.x;
    if (blockIdx.x == 0) {
        if (t < 128) {
            // v[t] = proj_w row t . w_st
            float acc = 0.f;
            for (int j = 0; j < D; ++j) acc += proj_w[t * D + j] * w_st[j];
            ws[WS_V + t] = acc;
        } else if (t == 128) {
            float acc = 0.f;
            for (int j = 0; j < D; ++j) acc += proj_b[j] * w_st[j];
            ws[WS_C] = acc;
        } else if (t >= 136 && t < 144) {
            int b = t - 136;
            int uid = user_id[b];
            float th = theta[uid];   // theta is (NST,1)
            float acc = 0.f;
            for (int dd = 0; dd < D; ++dd)
                acc += ((1.f - th) * user_embedding[b * D + dd] +
                        th * user_emb_table[(size_t)uid * D + dd]) * w_u[dd];
            ws[WS_UC + b] = acc + b_u[0] + b_st[0];
        }
        // all 256 threads: now_val for (b,k) = t
        {
            int n = now_nodes[t];
            float acc = 0.f;
            for (int dd = 0; dd < D; ++dd)
                acc += station_embedding[(size_t)n * D + dd] * w_st[dd];
            ws[WS_NOW + t] = alpha[n] * acc;
        }
    } else {
        // his_val: one 64-lane wave per gathered row. wid in [0,256)
        int wid  = (blockIdx.x - 1) * 4 + (t >> 6);
        int lane = t & 63;
        int n = his_nodes[wid];
        // fold second linear: v2[lane] = w_his2 row lane . w_st ; c2 = b_his2 . w_st
        float v2 = 0.f, c2 = 0.f;
        for (int dd = 0; dd < D; ++dd) {
            float wst = w_st[dd];
            v2 += w_his2[lane * D + dd] * wst;
            c2 += b_his2[dd] * wst;
        }
        // layer 1, hidden unit = lane (D/2 == 64). Coalesced down w_his1 columns.
        float h1 = b_his1[lane];
        for (int dd = 0; dd < D; ++dd)
            h1 += raw_field_embed[(size_t)n * D + dd] * w_his1[dd * 64 + lane];
        float h1a = h1 > 0.f ? h1 : 0.01f * h1;   // jax leaky_relu default slope
        float contrib = h1a * v2;
        for (int off = 32; off >= 1; off >>= 1)
            contrib += __shfl_down(contrib, off, 64);
        if (lane == 0)
            ws[WS_HIS + wid] = alpha[n] * (contrib + c2);
    }
}

// main: out[b,n] = s[n] + uc[b] for all (b,n); s[n] = station_emb_table[n].v + c
__global__ __launch_bounds__(256) void k_main(
    const float* __restrict__ set,   // station_emb_table
    const float* __restrict__ ws,
    float* __restrict__ out)
{
    __shared__ float s_v[128];
    __shared__ float s_tile[64];
    __shared__ float s_uc[8];
    __shared__ float s_c;
    const int t = threadIdx.x;
    if (t < 128) s_v[t] = ws[WS_V + t];
    if (t == 128) s_c = ws[WS_C];
    if (t >= 136 && t < 144) s_uc[t - 136] = ws[WS_UC + t - 136];
    __syncthreads();

    const int row0 = blockIdx.x * 64;
    const int w    = t >> 6;
    const int lane = t & 63;
    const int half = lane >> 5;
    const int l32  = lane & 31;
    const float4 vv = ((const float4*)s_v)[l32];
    const float  c  = s_c;

    // wave reads rows R (lanes 0-31) and R+1 (lanes 32-63): 1024 B contiguous
    for (int i = 0; i < 8; ++i) {
        int r = i * 8 + w * 2 + half;
        int row = row0 + r;
        float acc = 0.f;
        if (row < NU) {
            float4 x = ((const float4*)(set + (size_t)row * D))[l32];
            acc = x.x * vv.x + x.y * vv.y + x.z * vv.z + x.w * vv.w;
        }
        for (int off = 16; off >= 1; off >>= 1)
            acc += __shfl_down(acc, off, 32);   // reduce within each 32-lane half
        if (l32 == 0) s_tile[r] = acc + c;
    }
    __syncthreads();

    // coalesced write of all 8 batch copies
    const int nl = t & 63;
    const int b0 = t >> 6;          // 0..3
    const int row = row0 + nl;
    if (row < NU) {
        float sv = s_tile[nl];
        out[(size_t)b0 * NU + row]       = sv + s_uc[b0];
        out[(size_t)(b0 + 4) * NU + row] = sv + s_uc[b0 + 4];
    }
}

// fix-up of the <=512 scattered entries (runs after k_main on the same stream)
__global__ __launch_bounds__(512) void k_fix(
    const float* __restrict__ set,
    const float* __restrict__ alpha,
    const int* __restrict__ his_nodes,
    const int* __restrict__ now_nodes,
    const float* __restrict__ ws,
    float* __restrict__ out)
{
    __shared__ int   s_nodes[B][64];
    __shared__ float s_vals[B][64];
    __shared__ float s_v[128];
    __shared__ float s_c;
    const int t = threadIdx.x;
    const int b = t >> 6;
    const int j = t & 63;
    if (t < 128) s_v[t] = ws[WS_V + t];
    if (t == 128) s_c = ws[WS_C];
    if (j < K) {
        s_nodes[b][j] = now_nodes[b * K + j];
        s_vals[b][j]  = ws[WS_NOW + b * K + j];
    } else {
        s_nodes[b][j] = his_nodes[b * K + (j - K)];
        s_vals[b][j]  = ws[WS_HIS + b * K + (j - K)];
    }
    __syncthreads();
    int n = s_nodes[b][j];
    // only first occurrence within the batch row processes node n
    bool first = true;
    for (int i = 0; i < j; ++i)
        if (s_nodes[b][i] == n) { first = false; break; }
    if (!first) return;
    // JAX .add semantics: duplicates accumulate — sum every matching slot
    float sum = 0.f;
    for (int i = 0; i < 64; ++i)
        if (s_nodes[b][i] == n) sum += s_vals[b][i];
    float sn = s_c;
    for (int dd = 0; dd < D; ++dd)
        sn += set[(size_t)n * D + dd] * s_v[dd];
    out[(size_t)b * NU + n] = (1.f - alpha[n]) * sn + ws[WS_UC + b] + sum;
}

extern "C" void kernel_launch(void* const* d_in, const int* in_sizes, int n_in,
                              void* d_out, int out_size, void* d_ws, size_t ws_size,
                              hipStream_t stream) {
    const float* user_embedding    = (const float*)d_in[0];
    const float* station_embedding = (const float*)d_in[1];
    const float* raw_field_embed   = (const float*)d_in[2];
    const int*   his_nodes         = (const int*)d_in[3];
    const int*   now_nodes         = (const int*)d_in[4];
    const int*   user_id           = (const int*)d_in[5];
    const float* user_emb_table    = (const float*)d_in[6];
    const float* station_emb_table = (const float*)d_in[7];
    const float* proj_w            = (const float*)d_in[8];
    const float* proj_b            = (const float*)d_in[9];
    const float* theta             = (const float*)d_in[10];
    const float* alpha             = (const float*)d_in[11];
    const float* w_his1            = (const float*)d_in[12];
    const float* b_his1            = (const float*)d_in[13];
    const float* w_his2            = (const float*)d_in[14];
    const float* b_his2            = (const float*)d_in[15];
    const float* w_st              = (const float*)d_in[16];
    const float* b_st              = (const float*)d_in[17];
    const float* w_u               = (const float*)d_in[18];
    const float* b_u               = (const float*)d_in[19];
    float* out = (float*)d_out;
    float* ws  = (float*)d_ws;

    hipLaunchKernelGGL(k_prep, dim3(65), dim3(256), 0, stream,
                       user_embedding, station_embedding, raw_field_embed,
                       his_nodes, now_nodes, user_id, user_emb_table,
                       proj_w, proj_b, theta, alpha,
                       w_his1, b_his1, w_his2, b_his2,
                       w_st, b_st, w_u, b_u, ws);

    hipLaunchKernelGGL(k_main, dim3((NU + 63) / 64), dim3(256), 0, stream,
                       station_emb_table, ws, out);

    hipLaunchKernelGGL(k_fix, dim3(1), dim3(512), 0, stream,
                       station_emb_table, alpha, his_nodes, now_nodes, ws, out);
}